// Round 6
// baseline (809.304 us; speedup 1.0000x reference)
//
#include <hip/hip_runtime.h>

#define BS 4
#define SEQ 2048
#define DIM 1024
#define NH 16
#define HD 64
#define T_TOK (BS * SEQ)   // 8192

using f32x4 = __attribute__((ext_vector_type(4))) float;
using s16x8 = __attribute__((ext_vector_type(8))) short;
using u32x4 = __attribute__((ext_vector_type(4))) unsigned int;

// bf16 copies of inputs/weights live in module bss (not d_ws): 56 MB total.
__device__ unsigned short g_qbf[T_TOK * DIM];
__device__ unsigned short g_kbf[T_TOK * DIM];
__device__ unsigned short g_vbf[T_TOK * DIM];
__device__ unsigned short g_wbf[4][DIM * DIM];

static __device__ __forceinline__ unsigned short f2bf(float f) {
    unsigned int u = __float_as_uint(f);
    u += 0x7FFF + ((u >> 16) & 1);   // RNE
    return (unsigned short)(u >> 16);
}

// async 16B global->LDS (GEMM staging only; flash reverted to reg-staging —
// rounds 3-5 showed gload_lds K/V streams defeat L2 reuse: FETCH 139MB->930MB).
static __device__ __forceinline__ void gload16(const void* g, void* l) {
    __builtin_amdgcn_global_load_lds((const __attribute__((address_space(1))) void*)g,
                                     (__attribute__((address_space(3))) void*)l, 16, 0, 0);
}

// f32 -> bf16 bulk converters (one launch for q,k,v; one for the 4 weights)
__global__ __launch_bounds__(256) void cvt_in(const float* __restrict__ q,
                                              const float* __restrict__ k,
                                              const float* __restrict__ v) {
    const float* s; unsigned short* d;
    if (blockIdx.y == 0)      { s = q; d = g_qbf; }
    else if (blockIdx.y == 1) { s = k; d = g_kbf; }
    else                      { s = v; d = g_vbf; }
    const long i = ((long)blockIdx.x * 256 + threadIdx.x) * 8;
    f32x4 a = *(const f32x4*)(s + i);
    f32x4 b = *(const f32x4*)(s + i + 4);
    s16x8 o;
    o[0] = (short)f2bf(a[0]); o[1] = (short)f2bf(a[1]);
    o[2] = (short)f2bf(a[2]); o[3] = (short)f2bf(a[3]);
    o[4] = (short)f2bf(b[0]); o[5] = (short)f2bf(b[1]);
    o[6] = (short)f2bf(b[2]); o[7] = (short)f2bf(b[3]);
    *(s16x8*)(d + i) = o;
}

__global__ __launch_bounds__(256) void cvt_w(const float* __restrict__ w0,
                                             const float* __restrict__ w1,
                                             const float* __restrict__ w2,
                                             const float* __restrict__ w3) {
    const float* s;
    if (blockIdx.y == 0)      s = w0;
    else if (blockIdx.y == 1) s = w1;
    else if (blockIdx.y == 2) s = w2;
    else                      s = w3;
    unsigned short* d = g_wbf[blockIdx.y];
    const long i = ((long)blockIdx.x * 256 + threadIdx.x) * 8;
    f32x4 a = *(const f32x4*)(s + i);
    f32x4 b = *(const f32x4*)(s + i + 4);
    s16x8 o;
    o[0] = (short)f2bf(a[0]); o[1] = (short)f2bf(a[1]);
    o[2] = (short)f2bf(a[2]); o[3] = (short)f2bf(a[3]);
    o[4] = (short)f2bf(b[0]); o[5] = (short)f2bf(b[1]);
    o[6] = (short)f2bf(b[2]); o[7] = (short)f2bf(b[3]);
    *(s16x8*)(d + i) = o;
}

// swizzled LDS read: logical (row, col-elem kel) lives at byte
// (row*128 + kel*2) ^ ((row&7)<<4)
static __device__ __forceinline__ s16x8 lds_frag(const unsigned short* lds, int row, int kel) {
    int byte = (row * 128 + kel * 2) ^ ((row & 7) << 4);
    return *(const s16x8*)((const char*)lds + byte);
}

// C = A * B^T, epilogue (acc+bias)*alpha. A: bf16 [M][K]; B: bf16 [N][K].
template<int ASEL, int WSEL, bool TRANS_OUT, bool OUT_BF16>
__global__ __launch_bounds__(256, 2)
void gemm_bt(const void* __restrict__ Ap, const float* __restrict__ bias, float alpha,
             void* __restrict__ Cp, int K, long ldc) {
    __shared__ unsigned short As[128 * 64];
    __shared__ unsigned short Bs[128 * 64];

    const unsigned short* A = (ASEL == 0) ? g_qbf : (ASEL == 1) ? g_kbf
                              : (ASEL == 2) ? g_vbf : (const unsigned short*)Ap;
    const unsigned short* B = g_wbf[WSEL];

    const int tid = threadIdx.x;
    const int lane = tid & 63;
    const int wid = tid >> 6;
    const long bm = (long)blockIdx.x * 128;
    const long bn = (long)blockIdx.y * 128;
    const int wm = (wid >> 1) * 64;
    const int wn = (wid & 1) * 64;

    f32x4 acc[4][4] = {};

#pragma unroll 1
    for (int k0 = 0; k0 < K; k0 += 64) {
#pragma unroll
        for (int p = 0; p < 4; ++p) {
            const int cbase = (p * 4 + wid) * 1024;     // wave-uniform LDS chunk
            const int e = cbase + lane * 16;            // linear LDS byte this lane fills
            const int row = e >> 7;                     // 128 B per tile row
            const int gc = (e ^ ((row & 7) << 4)) & 127;  // pre-swizzled col byte
            gload16((const char*)A + ((bm + row) * K + k0) * 2 + gc, (char*)As + cbase);
            gload16((const char*)B + ((bn + row) * K + k0) * 2 + gc, (char*)Bs + cbase);
        }
        __syncthreads();
#pragma unroll
        for (int kk = 0; kk < 2; ++kk) {
            const int kel = kk * 32 + (lane >> 4) * 8;
            s16x8 af[4], bf[4];
#pragma unroll
            for (int i = 0; i < 4; ++i) {
                af[i] = lds_frag(As, wm + i * 16 + (lane & 15), kel);
                bf[i] = lds_frag(Bs, wn + i * 16 + (lane & 15), kel);
            }
#pragma unroll
            for (int i = 0; i < 4; ++i)
#pragma unroll
                for (int j = 0; j < 4; ++j) {
                    if constexpr (TRANS_OUT)
                        acc[i][j] = __builtin_amdgcn_mfma_f32_16x16x32_bf16(bf[j], af[i], acc[i][j], 0, 0, 0);
                    else
                        acc[i][j] = __builtin_amdgcn_mfma_f32_16x16x32_bf16(af[i], bf[j], acc[i][j], 0, 0, 0);
                }
        }
        __syncthreads();
    }

#pragma unroll
    for (int i = 0; i < 4; ++i)
#pragma unroll
        for (int j = 0; j < 4; ++j)
#pragma unroll
            for (int r = 0; r < 4; ++r) {
                if constexpr (!TRANS_OUT) {
                    long row = bm + wm + i * 16 + ((lane >> 4) * 4 + r);
                    long col = bn + wn + j * 16 + (lane & 15);
                    float v = (acc[i][j][r] + bias[col]) * alpha;
                    if constexpr (OUT_BF16)
                        ((unsigned short*)Cp)[row * ldc + col] = f2bf(v);
                    else
                        ((float*)Cp)[row * ldc + col] = v;
                } else {
                    long o = bn + wn + j * 16 + ((lane >> 4) * 4 + r);
                    long t = bm + wm + i * 16 + (lane & 15);
                    float v = (acc[i][j][r] + bias[o]) * alpha;
                    ((unsigned short*)Cp)[o * ldc + t] = f2bf(v);
                }
            }
}

// Flash attention v4: 512 blocks x 512 threads, 8 waves x 32 q-rows.
// Staging REVERTED to register path (linear global dwordx4 -> swizzled
// ds_write_b128), T14 async-split: issue tile t+1 loads BEFORE compute on
// tile t, ds_write after PV (compiler's vmcnt covers the dependency).
// gload_lds staging (rounds 3-5) killed L2 reuse: FETCH 139MB -> 930MB.
__global__ __launch_bounds__(512, 4)
void flash_attn(const unsigned short* __restrict__ Qb,
                const unsigned short* __restrict__ Kb,
                const unsigned short* __restrict__ Vt,
                const int* __restrict__ mask,
                unsigned short* __restrict__ Ctx) {
    __shared__ unsigned short Ks[2][64 * 64];
    __shared__ unsigned short Vts[2][64 * 64];
    __shared__ unsigned short Ps[256 * 64];
    __shared__ float masks[SEQ];

    const int tid = threadIdx.x;
    const int lane = tid & 63;
    const int w = tid >> 6;            // 0..7

    // pair-affinity: id = (pair%8) + 8*(qt + 8*(pair/8))
    const int f = blockIdx.x;
    const int qt_i = (f >> 3) & 7;
    const int pair = (f & 7) + 8 * (f >> 6);
    const int h = pair & 15;
    const int b = pair >> 4;
    const long qt = (long)qt_i * 256;
    const long base_t = (long)b * SEQ;

    // Q fragments in registers (A-operand: row=lane&15, k=(lane>>4)*8..+7)
    s16x8 qreg[2][2];
#pragma unroll
    for (int i = 0; i < 2; ++i)
#pragma unroll
        for (int kk = 0; kk < 2; ++kk)
            qreg[i][kk] = *(const s16x8*)(Qb + (base_t + qt + w * 32 + i * 16 + (lane & 15)) * DIM
                                          + h * 64 + kk * 32 + (lane >> 4) * 8);

    // per-thread staging coords: 512 threads cover one 64x128B tile.
    // Global read linear; swizzle applied on the LDS WRITE side (same XOR the
    // readers use -> rule 21 both-sides).
    const int st_row = tid >> 3;                       // tile row 0..63
    const int st_cb  = (tid & 7) * 16;                 // col byte 0..112
    const int st_lds = (tid * 16) ^ ((st_row & 7) << 4);  // swizzled LDS byte
    u32x4 kreg, vreg;
#define LOADKV(KV)                                                                                   \
    do {                                                                                             \
        kreg = *(const u32x4*)((const char*)Kb + ((base_t + (KV) + st_row) * DIM + h * 64) * 2 + st_cb); \
        vreg = *(const u32x4*)((const char*)Vt + (((long)h * 64 + st_row) * T_TOK + base_t + (KV)) * 2 + st_cb); \
    } while (0)
#define WRITEKV(BUF)                                                                                 \
    do {                                                                                             \
        *(u32x4*)((char*)Ks[BUF] + st_lds) = kreg;                                                   \
        *(u32x4*)((char*)Vts[BUF] + st_lds) = vreg;                                                  \
    } while (0)

    float m_st[2][4], l_st[2][4];
    f32x4 o_acc[2][4] = {};
#pragma unroll
    for (int i = 0; i < 2; ++i)
#pragma unroll
        for (int r = 0; r < 4; ++r) { m_st[i][r] = -1e30f; l_st[i][r] = 0.f; }

    LOADKV(0);
    for (int j = tid; j < SEQ; j += 512) masks[j] = mask[b * SEQ + j] ? 0.f : -1e30f;
    WRITEKV(0);
    __syncthreads();

    int cur = 0;
    const int NT = SEQ / 64;
#pragma unroll 1
    for (int t = 0; t < NT; ++t) {
        const int kv = t * 64;
        if (t + 1 < NT) LOADKV(kv + 64);   // issue early; consumed after PV

        const unsigned short* Kc = Ks[cur];
        const unsigned short* Vc = Vts[cur];

        // S = Q K^T
        f32x4 s[2][4] = {};
        __builtin_amdgcn_s_setprio(1);
#pragma unroll
        for (int kk = 0; kk < 2; ++kk) {
            const int kel = kk * 32 + (lane >> 4) * 8;
            s16x8 kf[4];
#pragma unroll
            for (int j = 0; j < 4; ++j) kf[j] = lds_frag(Kc, j * 16 + (lane & 15), kel);
#pragma unroll
            for (int i = 0; i < 2; ++i)
#pragma unroll
                for (int j = 0; j < 4; ++j)
                    s[i][j] = __builtin_amdgcn_mfma_f32_16x16x32_bf16(qreg[i][kk], kf[j], s[i][j], 0, 0, 0);
        }
        __builtin_amdgcn_s_setprio(0);

        // online softmax per q-row (row spread across 16 lanes sharing lane>>4)
#pragma unroll
        for (int i = 0; i < 2; ++i)
#pragma unroll
            for (int r = 0; r < 4; ++r) {
                float mx = -1e30f;
#pragma unroll
                for (int j = 0; j < 4; ++j) {
                    s[i][j][r] += masks[kv + j * 16 + (lane & 15)];
                    mx = fmaxf(mx, s[i][j][r]);
                }
                mx = fmaxf(mx, __shfl_xor(mx, 1));
                mx = fmaxf(mx, __shfl_xor(mx, 2));
                mx = fmaxf(mx, __shfl_xor(mx, 4));
                mx = fmaxf(mx, __shfl_xor(mx, 8));
                const float m_new = fmaxf(m_st[i][r], mx);
                const float corr = __expf(m_st[i][r] - m_new);
                float rs = 0.f;
#pragma unroll
                for (int j = 0; j < 4; ++j) {
                    float p = __expf(s[i][j][r] - m_new);
                    s[i][j][r] = p;
                    rs += p;
                }
                rs += __shfl_xor(rs, 1);
                rs += __shfl_xor(rs, 2);
                rs += __shfl_xor(rs, 4);
                rs += __shfl_xor(rs, 8);
                l_st[i][r] = l_st[i][r] * corr + rs;
                m_st[i][r] = m_new;
#pragma unroll
                for (int j = 0; j < 4; ++j) o_acc[i][j][r] *= corr;
                const int prow = w * 32 + i * 16 + (lane >> 4) * 4 + r;
#pragma unroll
                for (int j = 0; j < 4; ++j) {
                    const int pcol = j * 16 + (lane & 15);
                    const int byte = (prow * 128 + pcol * 2) ^ ((prow & 7) << 4);
                    *(unsigned short*)((char*)Ps + byte) = f2bf(s[i][j][r]);
                }
            }

        // O += P * V  (Ps rows are wave-private; same-wave lgkmcnt ordering)
        __builtin_amdgcn_s_setprio(1);
#pragma unroll
        for (int kk = 0; kk < 2; ++kk) {
            const int kel = kk * 32 + (lane >> 4) * 8;
            s16x8 pf[2], vf[4];
#pragma unroll
            for (int i = 0; i < 2; ++i) pf[i] = lds_frag(Ps, w * 32 + i * 16 + (lane & 15), kel);
#pragma unroll
            for (int j = 0; j < 4; ++j) vf[j] = lds_frag(Vc, j * 16 + (lane & 15), kel);
#pragma unroll
            for (int i = 0; i < 2; ++i)
#pragma unroll
                for (int j = 0; j < 4; ++j)
                    o_acc[i][j] = __builtin_amdgcn_mfma_f32_16x16x32_bf16(pf[i], vf[j], o_acc[i][j], 0, 0, 0);
        }
        __builtin_amdgcn_s_setprio(0);

        // write next tile into the free buffer (compiler waits vmcnt for regs);
        // end-of-iter barrier publishes it and closes reads of buf[cur].
        if (t + 1 < NT) WRITEKV(cur ^ 1);
        __syncthreads();
        cur ^= 1;
    }
#undef LOADKV
#undef WRITEKV

    // epilogue: normalize into Ps (linear, wave-private rows), barrier, then
    // coalesced 16B/lane stores (8 lanes = one full 128B Ctx row segment).
#pragma unroll
    for (int i = 0; i < 2; ++i)
#pragma unroll
        for (int j = 0; j < 4; ++j)
#pragma unroll
            for (int r = 0; r < 4; ++r) {
                const float vv = o_acc[i][j][r] / l_st[i][r];
                const int prow = w * 32 + i * 16 + (lane >> 4) * 4 + r;
                const int pcol = j * 16 + (lane & 15);
                Ps[prow * 64 + pcol] = f2bf(vv);
            }
    __syncthreads();
#pragma unroll
    for (int p = 0; p < 4; ++p) {
        const int e = (p * 512 + tid) * 8;   // element index in 256x64 tile
        const int row = e >> 6;
        const int col = e & 63;
        *(u32x4*)(Ctx + (base_t + qt + row) * DIM + h * 64 + col) = *(const u32x4*)(Ps + e);
    }
}

extern "C" void kernel_launch(void* const* d_in, const int* in_sizes, int n_in,
                              void* d_out, int out_size, void* d_ws, size_t ws_size,
                              hipStream_t stream) {
    const float* q  = (const float*)d_in[0];
    const float* k  = (const float*)d_in[1];
    const float* v  = (const float*)d_in[2];
    const int* mask = (const int*)d_in[3];
    const float* bq = (const float*)d_in[5];
    const float* bk = (const float*)d_in[7];
    const float* bv = (const float*)d_in[9];
    const float* bo = (const float*)d_in[11];
    float* out = (float*)d_out;

    // ws: Qb | Kb | Vt | Ctx  = 4 x 16 MB = 64 MB
    unsigned short* Qb  = (unsigned short*)d_ws;
    unsigned short* Kb  = Qb + (size_t)T_TOK * DIM;
    unsigned short* Vt  = Kb + (size_t)T_TOK * DIM;
    unsigned short* Ctx = Vt + (size_t)T_TOK * DIM;

    cvt_in<<<dim3(T_TOK * DIM / (256 * 8), 3), 256, 0, stream>>>(q, k, v);
    cvt_w <<<dim3(DIM * DIM / (256 * 8), 4), 256, 0, stream>>>(
        (const float*)d_in[4], (const float*)d_in[6], (const float*)d_in[8], (const float*)d_in[10]);

    const dim3 g(T_TOK / 128, DIM / 128);
    gemm_bt<0, 0, false, true><<<g, 256, 0, stream>>>(nullptr, bq, 0.125f, Qb, DIM, DIM);
    gemm_bt<1, 1, false, true><<<g, 256, 0, stream>>>(nullptr, bk, 1.0f, Kb, DIM, DIM);
    gemm_bt<2, 2, true,  true><<<g, 256, 0, stream>>>(nullptr, bv, 1.0f, Vt, DIM, T_TOK);

    flash_attn<<<dim3(512), 512, 0, stream>>>(Qb, Kb, Vt, mask, Ctx);

    gemm_bt<3, 3, false, false><<<g, 256, 0, stream>>>(Ctx, bo, 1.0f, out, DIM, DIM);
}

// Round 7
// 472.211 us; speedup vs baseline: 1.7139x; 1.7139x over previous
//
#include <hip/hip_runtime.h>

#define BS 4
#define SEQ 2048
#define DIM 1024
#define NH 16
#define HD 64
#define T_TOK (BS * SEQ)   // 8192

using f32x4 = __attribute__((ext_vector_type(4))) float;
using s16x8 = __attribute__((ext_vector_type(8))) short;
using u32x4 = __attribute__((ext_vector_type(4))) unsigned int;

// bf16 copies of inputs/weights live in module bss (not d_ws): 56 MB total.
__device__ unsigned short g_qbf[T_TOK * DIM];
__device__ unsigned short g_kbf[T_TOK * DIM];
__device__ unsigned short g_vbf[T_TOK * DIM];
__device__ unsigned short g_wbf[4][DIM * DIM];

static __device__ __forceinline__ unsigned short f2bf(float f) {
    unsigned int u = __float_as_uint(f);
    u += 0x7FFF + ((u >> 16) & 1);   // RNE
    return (unsigned short)(u >> 16);
}

// async 16B global->LDS (direct, no VGPR round-trip).
static __device__ __forceinline__ void gload16(const void* g, void* l) {
    __builtin_amdgcn_global_load_lds((const __attribute__((address_space(1))) void*)g,
                                     (__attribute__((address_space(3))) void*)l, 16, 0, 0);
}

// f32 -> bf16 bulk converters (one launch for q,k,v; one for the 4 weights)
__global__ __launch_bounds__(256) void cvt_in(const float* __restrict__ q,
                                              const float* __restrict__ k,
                                              const float* __restrict__ v) {
    const float* s; unsigned short* d;
    if (blockIdx.y == 0)      { s = q; d = g_qbf; }
    else if (blockIdx.y == 1) { s = k; d = g_kbf; }
    else                      { s = v; d = g_vbf; }
    const long i = ((long)blockIdx.x * 256 + threadIdx.x) * 8;
    f32x4 a = *(const f32x4*)(s + i);
    f32x4 b = *(const f32x4*)(s + i + 4);
    s16x8 o;
    o[0] = (short)f2bf(a[0]); o[1] = (short)f2bf(a[1]);
    o[2] = (short)f2bf(a[2]); o[3] = (short)f2bf(a[3]);
    o[4] = (short)f2bf(b[0]); o[5] = (short)f2bf(b[1]);
    o[6] = (short)f2bf(b[2]); o[7] = (short)f2bf(b[3]);
    *(s16x8*)(d + i) = o;
}

__global__ __launch_bounds__(256) void cvt_w(const float* __restrict__ w0,
                                             const float* __restrict__ w1,
                                             const float* __restrict__ w2,
                                             const float* __restrict__ w3) {
    const float* s;
    if (blockIdx.y == 0)      s = w0;
    else if (blockIdx.y == 1) s = w1;
    else if (blockIdx.y == 2) s = w2;
    else                      s = w3;
    unsigned short* d = g_wbf[blockIdx.y];
    const long i = ((long)blockIdx.x * 256 + threadIdx.x) * 8;
    f32x4 a = *(const f32x4*)(s + i);
    f32x4 b = *(const f32x4*)(s + i + 4);
    s16x8 o;
    o[0] = (short)f2bf(a[0]); o[1] = (short)f2bf(a[1]);
    o[2] = (short)f2bf(a[2]); o[3] = (short)f2bf(a[3]);
    o[4] = (short)f2bf(b[0]); o[5] = (short)f2bf(b[1]);
    o[6] = (short)f2bf(b[2]); o[7] = (short)f2bf(b[3]);
    *(s16x8*)(d + i) = o;
}

// swizzled LDS read: logical (row, col-elem kel) lives at byte
// (row*128 + kel*2) ^ ((row&7)<<4)
static __device__ __forceinline__ s16x8 lds_frag(const unsigned short* lds, int row, int kel) {
    int byte = (row * 128 + kel * 2) ^ ((row & 7) << 4);
    return *(const s16x8*)((const char*)lds + byte);
}

// C = A * B^T, epilogue (acc+bias)*alpha. A: bf16 [M][K]; B: bf16 [N][K].
template<int ASEL, int WSEL, bool TRANS_OUT, bool OUT_BF16>
__global__ __launch_bounds__(256, 2)
void gemm_bt(const void* __restrict__ Ap, const float* __restrict__ bias, float alpha,
             void* __restrict__ Cp, int K, long ldc) {
    __shared__ unsigned short As[128 * 64];
    __shared__ unsigned short Bs[128 * 64];

    const unsigned short* A = (ASEL == 0) ? g_qbf : (ASEL == 1) ? g_kbf
                              : (ASEL == 2) ? g_vbf : (const unsigned short*)Ap;
    const unsigned short* B = g_wbf[WSEL];

    const int tid = threadIdx.x;
    const int lane = tid & 63;
    const int wid = tid >> 6;
    const long bm = (long)blockIdx.x * 128;
    const long bn = (long)blockIdx.y * 128;
    const int wm = (wid >> 1) * 64;
    const int wn = (wid & 1) * 64;

    f32x4 acc[4][4] = {};

#pragma unroll 1
    for (int k0 = 0; k0 < K; k0 += 64) {
#pragma unroll
        for (int p = 0; p < 4; ++p) {
            const int cbase = (p * 4 + wid) * 1024;     // wave-uniform LDS chunk
            const int e = cbase + lane * 16;            // linear LDS byte this lane fills
            const int row = e >> 7;                     // 128 B per tile row
            const int gc = (e ^ ((row & 7) << 4)) & 127;  // pre-swizzled col byte
            gload16((const char*)A + ((bm + row) * K + k0) * 2 + gc, (char*)As + cbase);
            gload16((const char*)B + ((bn + row) * K + k0) * 2 + gc, (char*)Bs + cbase);
        }
        __syncthreads();
#pragma unroll
        for (int kk = 0; kk < 2; ++kk) {
            const int kel = kk * 32 + (lane >> 4) * 8;
            s16x8 af[4], bf[4];
#pragma unroll
            for (int i = 0; i < 4; ++i) {
                af[i] = lds_frag(As, wm + i * 16 + (lane & 15), kel);
                bf[i] = lds_frag(Bs, wn + i * 16 + (lane & 15), kel);
            }
#pragma unroll
            for (int i = 0; i < 4; ++i)
#pragma unroll
                for (int j = 0; j < 4; ++j) {
                    if constexpr (TRANS_OUT)
                        acc[i][j] = __builtin_amdgcn_mfma_f32_16x16x32_bf16(bf[j], af[i], acc[i][j], 0, 0, 0);
                    else
                        acc[i][j] = __builtin_amdgcn_mfma_f32_16x16x32_bf16(af[i], bf[j], acc[i][j], 0, 0, 0);
                }
        }
        __syncthreads();
    }

#pragma unroll
    for (int i = 0; i < 4; ++i)
#pragma unroll
        for (int j = 0; j < 4; ++j)
#pragma unroll
            for (int r = 0; r < 4; ++r) {
                if constexpr (!TRANS_OUT) {
                    long row = bm + wm + i * 16 + ((lane >> 4) * 4 + r);
                    long col = bn + wn + j * 16 + (lane & 15);
                    float v = (acc[i][j][r] + bias[col]) * alpha;
                    if constexpr (OUT_BF16)
                        ((unsigned short*)Cp)[row * ldc + col] = f2bf(v);
                    else
                        ((float*)Cp)[row * ldc + col] = v;
                } else {
                    long o = bn + wn + j * 16 + ((lane >> 4) * 4 + r);
                    long t = bm + wm + i * 16 + (lane & 15);
                    float v = (acc[i][j][r] + bias[o]) * alpha;
                    ((unsigned short*)Cp)[o * ldc + t] = f2bf(v);
                }
            }
}

// Flash attention v5: IDENTICAL to v4 except __launch_bounds__(512, 2).
// Rounds 3-6 all capped waves at 128 unified regs (64 arch + 64 acc) via the
// (…,4) bound -> per-iteration scratch spill (R6: WRITE_SIZE 736MB vs 16MB
// ideal) -> spill writeback storm + L2 KV-stream thrash (FETCH ~1GB).
// (512,2) lifts the cap to 256 unified: no spill, ~8 waves/CU (round-1 regime).
__global__ __launch_bounds__(512, 2)
void flash_attn(const unsigned short* __restrict__ Qb,
                const unsigned short* __restrict__ Kb,
                const unsigned short* __restrict__ Vt,
                const int* __restrict__ mask,
                unsigned short* __restrict__ Ctx) {
    __shared__ unsigned short Ks[2][64 * 64];
    __shared__ unsigned short Vts[2][64 * 64];
    __shared__ unsigned short Ps[256 * 64];
    __shared__ float masks[SEQ];

    const int tid = threadIdx.x;
    const int lane = tid & 63;
    const int w = tid >> 6;            // 0..7

    // pair-affinity: id = (pair%8) + 8*(qt + 8*(pair/8))
    const int f = blockIdx.x;
    const int qt_i = (f >> 3) & 7;
    const int pair = (f & 7) + 8 * (f >> 6);
    const int h = pair & 15;
    const int b = pair >> 4;
    const long qt = (long)qt_i * 256;
    const long base_t = (long)b * SEQ;

    // Q fragments in registers (A-operand: row=lane&15, k=(lane>>4)*8..+7)
    s16x8 qreg[2][2];
#pragma unroll
    for (int i = 0; i < 2; ++i)
#pragma unroll
        for (int kk = 0; kk < 2; ++kk)
            qreg[i][kk] = *(const s16x8*)(Qb + (base_t + qt + w * 32 + i * 16 + (lane & 15)) * DIM
                                          + h * 64 + kk * 32 + (lane >> 4) * 8);

    // per-thread staging coords: 512 threads cover one 64x128B tile.
    // Global read linear; swizzle applied on the LDS WRITE side (same XOR the
    // readers use -> rule 21 both-sides).
    const int st_row = tid >> 3;                       // tile row 0..63
    const int st_cb  = (tid & 7) * 16;                 // col byte 0..112
    const int st_lds = (tid * 16) ^ ((st_row & 7) << 4);  // swizzled LDS byte
    u32x4 kreg, vreg;
#define LOADKV(KV)                                                                                   \
    do {                                                                                             \
        kreg = *(const u32x4*)((const char*)Kb + ((base_t + (KV) + st_row) * DIM + h * 64) * 2 + st_cb); \
        vreg = *(const u32x4*)((const char*)Vt + (((long)h * 64 + st_row) * T_TOK + base_t + (KV)) * 2 + st_cb); \
    } while (0)
#define WRITEKV(BUF)                                                                                 \
    do {                                                                                             \
        *(u32x4*)((char*)Ks[BUF] + st_lds) = kreg;                                                   \
        *(u32x4*)((char*)Vts[BUF] + st_lds) = vreg;                                                  \
    } while (0)

    float m_st[2][4], l_st[2][4];
    f32x4 o_acc[2][4] = {};
#pragma unroll
    for (int i = 0; i < 2; ++i)
#pragma unroll
        for (int r = 0; r < 4; ++r) { m_st[i][r] = -1e30f; l_st[i][r] = 0.f; }

    LOADKV(0);
    for (int j = tid; j < SEQ; j += 512) masks[j] = mask[b * SEQ + j] ? 0.f : -1e30f;
    WRITEKV(0);
    __syncthreads();

    int cur = 0;
    const int NT = SEQ / 64;
#pragma unroll 1
    for (int t = 0; t < NT; ++t) {
        const int kv = t * 64;
        if (t + 1 < NT) LOADKV(kv + 64);   // issue early; consumed after PV

        const unsigned short* Kc = Ks[cur];
        const unsigned short* Vc = Vts[cur];

        // S = Q K^T
        f32x4 s[2][4] = {};
        __builtin_amdgcn_s_setprio(1);
#pragma unroll
        for (int kk = 0; kk < 2; ++kk) {
            const int kel = kk * 32 + (lane >> 4) * 8;
            s16x8 kf[4];
#pragma unroll
            for (int j = 0; j < 4; ++j) kf[j] = lds_frag(Kc, j * 16 + (lane & 15), kel);
#pragma unroll
            for (int i = 0; i < 2; ++i)
#pragma unroll
                for (int j = 0; j < 4; ++j)
                    s[i][j] = __builtin_amdgcn_mfma_f32_16x16x32_bf16(qreg[i][kk], kf[j], s[i][j], 0, 0, 0);
        }
        __builtin_amdgcn_s_setprio(0);

        // online softmax per q-row (row spread across 16 lanes sharing lane>>4)
#pragma unroll
        for (int i = 0; i < 2; ++i)
#pragma unroll
            for (int r = 0; r < 4; ++r) {
                float mx = -1e30f;
#pragma unroll
                for (int j = 0; j < 4; ++j) {
                    s[i][j][r] += masks[kv + j * 16 + (lane & 15)];
                    mx = fmaxf(mx, s[i][j][r]);
                }
                mx = fmaxf(mx, __shfl_xor(mx, 1));
                mx = fmaxf(mx, __shfl_xor(mx, 2));
                mx = fmaxf(mx, __shfl_xor(mx, 4));
                mx = fmaxf(mx, __shfl_xor(mx, 8));
                const float m_new = fmaxf(m_st[i][r], mx);
                const float corr = __expf(m_st[i][r] - m_new);
                float rs = 0.f;
#pragma unroll
                for (int j = 0; j < 4; ++j) {
                    float p = __expf(s[i][j][r] - m_new);
                    s[i][j][r] = p;
                    rs += p;
                }
                rs += __shfl_xor(rs, 1);
                rs += __shfl_xor(rs, 2);
                rs += __shfl_xor(rs, 4);
                rs += __shfl_xor(rs, 8);
                l_st[i][r] = l_st[i][r] * corr + rs;
                m_st[i][r] = m_new;
#pragma unroll
                for (int j = 0; j < 4; ++j) o_acc[i][j][r] *= corr;
                const int prow = w * 32 + i * 16 + (lane >> 4) * 4 + r;
#pragma unroll
                for (int j = 0; j < 4; ++j) {
                    const int pcol = j * 16 + (lane & 15);
                    const int byte = (prow * 128 + pcol * 2) ^ ((prow & 7) << 4);
                    *(unsigned short*)((char*)Ps + byte) = f2bf(s[i][j][r]);
                }
            }

        // O += P * V  (Ps rows are wave-private; same-wave lgkmcnt ordering)
        __builtin_amdgcn_s_setprio(1);
#pragma unroll
        for (int kk = 0; kk < 2; ++kk) {
            const int kel = kk * 32 + (lane >> 4) * 8;
            s16x8 pf[2], vf[4];
#pragma unroll
            for (int i = 0; i < 2; ++i) pf[i] = lds_frag(Ps, w * 32 + i * 16 + (lane & 15), kel);
#pragma unroll
            for (int j = 0; j < 4; ++j) vf[j] = lds_frag(Vc, j * 16 + (lane & 15), kel);
#pragma unroll
            for (int i = 0; i < 2; ++i)
#pragma unroll
                for (int j = 0; j < 4; ++j)
                    o_acc[i][j] = __builtin_amdgcn_mfma_f32_16x16x32_bf16(pf[i], vf[j], o_acc[i][j], 0, 0, 0);
        }
        __builtin_amdgcn_s_setprio(0);

        // write next tile into the free buffer (compiler waits vmcnt for regs);
        // end-of-iter barrier publishes it and closes reads of buf[cur].
        if (t + 1 < NT) WRITEKV(cur ^ 1);
        __syncthreads();
        cur ^= 1;
    }
#undef LOADKV
#undef WRITEKV

    // epilogue: normalize into Ps (linear, wave-private rows), barrier, then
    // coalesced 16B/lane stores (8 lanes = one full 128B Ctx row segment).
#pragma unroll
    for (int i = 0; i < 2; ++i)
#pragma unroll
        for (int j = 0; j < 4; ++j)
#pragma unroll
            for (int r = 0; r < 4; ++r) {
                const float vv = o_acc[i][j][r] / l_st[i][r];
                const int prow = w * 32 + i * 16 + (lane >> 4) * 4 + r;
                const int pcol = j * 16 + (lane & 15);
                Ps[prow * 64 + pcol] = f2bf(vv);
            }
    __syncthreads();
#pragma unroll
    for (int p = 0; p < 4; ++p) {
        const int e = (p * 512 + tid) * 8;   // element index in 256x64 tile
        const int row = e >> 6;
        const int col = e & 63;
        *(u32x4*)(Ctx + (base_t + qt + row) * DIM + h * 64 + col) = *(const u32x4*)(Ps + e);
    }
}

extern "C" void kernel_launch(void* const* d_in, const int* in_sizes, int n_in,
                              void* d_out, int out_size, void* d_ws, size_t ws_size,
                              hipStream_t stream) {
    const float* q  = (const float*)d_in[0];
    const float* k  = (const float*)d_in[1];
    const float* v  = (const float*)d_in[2];
    const int* mask = (const int*)d_in[3];
    const float* bq = (const float*)d_in[5];
    const float* bk = (const float*)d_in[7];
    const float* bv = (const float*)d_in[9];
    const float* bo = (const float*)d_in[11];
    float* out = (float*)d_out;

    // ws: Qb | Kb | Vt | Ctx  = 4 x 16 MB = 64 MB
    unsigned short* Qb  = (unsigned short*)d_ws;
    unsigned short* Kb  = Qb + (size_t)T_TOK * DIM;
    unsigned short* Vt  = Kb + (size_t)T_TOK * DIM;
    unsigned short* Ctx = Vt + (size_t)T_TOK * DIM;

    cvt_in<<<dim3(T_TOK * DIM / (256 * 8), 3), 256, 0, stream>>>(q, k, v);
    cvt_w <<<dim3(DIM * DIM / (256 * 8), 4), 256, 0, stream>>>(
        (const float*)d_in[4], (const float*)d_in[6], (const float*)d_in[8], (const float*)d_in[10]);

    const dim3 g(T_TOK / 128, DIM / 128);
    gemm_bt<0, 0, false, true><<<g, 256, 0, stream>>>(nullptr, bq, 0.125f, Qb, DIM, DIM);
    gemm_bt<1, 1, false, true><<<g, 256, 0, stream>>>(nullptr, bk, 1.0f, Kb, DIM, DIM);
    gemm_bt<2, 2, true,  true><<<g, 256, 0, stream>>>(nullptr, bv, 1.0f, Vt, DIM, T_TOK);

    flash_attn<<<dim3(512), 512, 0, stream>>>(Qb, Kb, Vt, mask, Ctx);

    gemm_bt<3, 3, false, false><<<g, 256, 0, stream>>>(Ctx, bo, 1.0f, out, DIM, DIM);
}